// Round 1
// baseline (2624.885 us; speedup 1.0000x reference)
//
#include <hip/hip_runtime.h>

// ---------------------------------------------------------------------------
// UFGConv: out = sum_b A_b * (filter_b . (A_b * (x @ W)))
// N=100000, F=128, E=3.2M per branch (3 branches).
// Strategy: GEMM -> per branch {build CSR, spmm1 (fused filter), spmm2 (+=out)}
// ---------------------------------------------------------------------------

__global__ __launch_bounds__(256) void gemm128(const float* __restrict__ x,
                                               const float* __restrict__ w,
                                               float* __restrict__ y, int n) {
  __shared__ float4 wsh[128][32];  // W row-major as float4 groups, 64 KB
  __shared__ float xsh[8][128];    // 8 rows of x, 4 KB
  const int tid = threadIdx.x;
  for (int i = tid; i < 128 * 32; i += 256)
    wsh[i >> 5][i & 31] = ((const float4*)w)[i];
  const int rowbase = blockIdx.x * 8;
  for (int i = tid; i < 8 * 128; i += 256) {
    int r = rowbase + (i >> 7);
    xsh[i >> 7][i & 127] = (r < n) ? x[(size_t)r * 128 + (i & 127)] : 0.f;
  }
  __syncthreads();
  const int r = tid >> 5, cg = tid & 31;
  float4 acc = {0.f, 0.f, 0.f, 0.f};
#pragma unroll
  for (int k = 0; k < 128; ++k) {
    float xv = xsh[r][k];
    float4 wv = wsh[k][cg];
    acc.x += xv * wv.x;
    acc.y += xv * wv.y;
    acc.z += xv * wv.z;
    acc.w += xv * wv.w;
  }
  if (rowbase + r < n) ((float4*)y)[(size_t)(rowbase + r) * 32 + cg] = acc;
}

__global__ void hist_kernel(const int* __restrict__ rows, int* counts, int E) {
  int e = blockIdx.x * 256 + threadIdx.x;
  if (e < E) atomicAdd(&counts[rows[e]], 1);
}

// Block-level exclusive scan (1024/block), emits block sums.
__global__ __launch_bounds__(1024) void scan1(const int* __restrict__ counts,
                                              int* __restrict__ rowptr,
                                              int* __restrict__ bsum, int n) {
  __shared__ int sh[1024];
  const int tid = threadIdx.x;
  const int i = blockIdx.x * 1024 + tid;
  int v = (i < n) ? counts[i] : 0;
  sh[tid] = v;
  __syncthreads();
  for (int off = 1; off < 1024; off <<= 1) {
    int t = (tid >= off) ? sh[tid - off] : 0;
    __syncthreads();
    sh[tid] += t;
    __syncthreads();
  }
  if (i < n) rowptr[i] = sh[tid] - v;  // exclusive
  if (tid == 1023) bsum[blockIdx.x] = sh[1023];
}

__global__ void scan2(int* bsum, int* rowptr, int nb, int n) {
  if (threadIdx.x == 0 && blockIdx.x == 0) {
    int run = 0;
    for (int b = 0; b < nb; ++b) {
      int t = bsum[b];
      bsum[b] = run;
      run += t;
    }
    rowptr[n] = run;  // == E
  }
}

__global__ __launch_bounds__(1024) void scan3(int* __restrict__ rowptr,
                                              int* __restrict__ offsets,
                                              const int* __restrict__ bsum, int n) {
  int i = blockIdx.x * 1024 + threadIdx.x;
  if (i < n) {
    int v = rowptr[i] + bsum[blockIdx.x];
    rowptr[i] = v;
    offsets[i] = v;  // running cursors for scatter
  }
}

__global__ void scatter_kernel(const int* __restrict__ rows,
                               const int* __restrict__ cols,
                               const float* __restrict__ vals, int* offsets,
                               int* __restrict__ cols_s, float* __restrict__ vals_s,
                               int E) {
  int e = blockIdx.x * 256 + threadIdx.x;
  if (e < E) {
    int p = atomicAdd(&offsets[rows[e]], 1);
    cols_s[p] = cols[e];
    vals_s[p] = vals[e];
  }
}

// One block (128 threads) per row; thread f owns feature f.
__global__ __launch_bounds__(128) void spmm_csr(const int* __restrict__ rowptr,
                                                const int* __restrict__ cols,
                                                const float* __restrict__ vals,
                                                const float* __restrict__ src,
                                                float* __restrict__ dst,
                                                const float* __restrict__ filt,
                                                int accumulate) {
  const int row = blockIdx.x;
  const int f = threadIdx.x;
  const int e0 = rowptr[row], e1 = rowptr[row + 1];
  float acc = 0.f;
  int e = e0;
  for (; e + 1 < e1; e += 2) {
    int c0 = cols[e], c1 = cols[e + 1];
    float v0 = vals[e], v1 = vals[e + 1];
    float s0 = src[(size_t)c0 * 128 + f];
    float s1 = src[(size_t)c1 * 128 + f];
    acc += v0 * s0;
    acc += v1 * s1;
  }
  if (e < e1) acc += vals[e] * src[(size_t)cols[e] * 128 + f];
  if (filt) acc *= filt[row];
  float* o = &dst[(size_t)row * 128 + f];
  *o = accumulate ? (*o + acc) : acc;
}

// ---- fallback (small workspace): COO atomic scatter -----------------------
__global__ void spmm_coo_atomic(const int* __restrict__ idx,
                                const float* __restrict__ vals,
                                const float* __restrict__ src, float* dst, int E) {
  long long t = (long long)blockIdx.x * 256 + threadIdx.x;
  int e = (int)(t >> 5);
  if (e >= E) return;
  int fg = ((int)t & 31) * 4;
  int r = idx[e], c = idx[E + e];
  float v = vals[e];
  float4 s = *(const float4*)&src[(size_t)c * 128 + fg];
  float* o = &dst[(size_t)r * 128 + fg];
  atomicAdd(o + 0, v * s.x);
  atomicAdd(o + 1, v * s.y);
  atomicAdd(o + 2, v * s.z);
  atomicAdd(o + 3, v * s.w);
}

__global__ void scale_rows(float* t, const float* __restrict__ filt, int n) {
  int i = blockIdx.x * 256 + threadIdx.x;
  if (i < n) t[i] *= filt[i >> 7];
}

extern "C" void kernel_launch(void* const* d_in, const int* in_sizes, int n_in,
                              void* d_out, int out_size, void* d_ws, size_t ws_size,
                              hipStream_t stream) {
  const float* x = (const float*)d_in[0];
  const float* w = (const float*)d_in[1];
  const float* filt[3] = {(const float*)d_in[2], (const float*)d_in[3],
                          (const float*)d_in[4]};
  const int* idx[3] = {(const int*)d_in[5], (const int*)d_in[7],
                       (const int*)d_in[9]};
  const float* val[3] = {(const float*)d_in[6], (const float*)d_in[8],
                         (const float*)d_in[10]};
  const int N = in_sizes[2];  // filter1 is [N,1]
  const int E = in_sizes[6];  // val1 is [E]
  float* out = (float*)d_out;

  char* ws = (char*)d_ws;
  const size_t NF = (size_t)N * 128 * sizeof(float);
  float* xW = (float*)ws;
  float* t = (float*)(ws + NF);
  size_t off = 2 * NF;
  int* rowptr = (int*)(ws + off);
  off += (((size_t)(N + 1) * 4) + 255) & ~(size_t)255;
  int* offsets = (int*)(ws + off);
  off += (((size_t)N * 4) + 255) & ~(size_t)255;
  int* bsum = (int*)(ws + off);
  off += 4096;
  int* cols_s = (int*)(ws + off);
  off += (size_t)E * 4;
  float* vals_s = (float*)(ws + off);
  off += (size_t)E * 4;
  const bool csr_ok = (ws_size >= off);

  // 1) xW = x @ W
  gemm128<<<(N + 7) / 8, 256, 0, stream>>>(x, w, xW, N);

  // 2) out = 0
  hipMemsetAsync(out, 0, (size_t)out_size * sizeof(float), stream);

  const int nb = (N + 1023) / 1024;
  for (int b = 0; b < 3; ++b) {
    if (csr_ok) {
      hipMemsetAsync(offsets, 0, (size_t)N * 4, stream);
      hist_kernel<<<(E + 255) / 256, 256, 0, stream>>>(idx[b], offsets, E);
      scan1<<<nb, 1024, 0, stream>>>(offsets, rowptr, bsum, N);
      scan2<<<1, 64, 0, stream>>>(bsum, rowptr, nb, N);
      scan3<<<nb, 1024, 0, stream>>>(rowptr, offsets, bsum, N);
      scatter_kernel<<<(E + 255) / 256, 256, 0, stream>>>(
          idx[b], idx[b] + E, val[b], offsets, cols_s, vals_s, E);
      // t = filter_b . (A_b * xW)
      spmm_csr<<<N, 128, 0, stream>>>(rowptr, cols_s, vals_s, xW, t, filt[b], 0);
      // out += A_b * t
      spmm_csr<<<N, 128, 0, stream>>>(rowptr, cols_s, vals_s, t, out, nullptr, 1);
    } else {
      hipMemsetAsync(t, 0, NF, stream);
      long long thr = (long long)E * 32;
      spmm_coo_atomic<<<(thr + 255) / 256, 256, 0, stream>>>(idx[b], val[b], xW,
                                                             t, E);
      scale_rows<<<((N * 128) + 255) / 256, 256, 0, stream>>>(t, filt[b],
                                                              N * 128);
      spmm_coo_atomic<<<(thr + 255) / 256, 256, 0, stream>>>(idx[b], val[b], t,
                                                             out, E);
    }
  }
}

// Round 3
// 2484.015 us; speedup vs baseline: 1.0567x; 1.0567x over previous
//
#include <hip/hip_runtime.h>
#include <hip/hip_bf16.h>

// ---------------------------------------------------------------------------
// UFGConv: out = sum_b A_b * (filter_b . (A_b * (x @ W)))
// N=100000, F=128, E=3.2M per branch (3 branches).
// R3: bf16 intermediates (halve gather traffic), int2 fused edge scatter,
//     no out memset (branch 0 writes, branches 1-2 accumulate).
//     Fix: bit_cast instead of .data (not exposed in this ROCm).
// ---------------------------------------------------------------------------

static __device__ __forceinline__ unsigned short bf16bits(float v) {
  return __builtin_bit_cast(unsigned short, __float2bfloat16(v));
}

__global__ __launch_bounds__(256) void gemm128(const float* __restrict__ x,
                                               const float* __restrict__ w,
                                               __hip_bfloat16* __restrict__ y,
                                               int n) {
  __shared__ float4 wsh[128][32];  // W row-major as float4 groups, 64 KB
  __shared__ float xsh[8][128];    // 8 rows of x, 4 KB
  const int tid = threadIdx.x;
  for (int i = tid; i < 128 * 32; i += 256)
    wsh[i >> 5][i & 31] = ((const float4*)w)[i];
  const int rowbase = blockIdx.x * 8;
  for (int i = tid; i < 8 * 128; i += 256) {
    int r = rowbase + (i >> 7);
    xsh[i >> 7][i & 127] = (r < n) ? x[(size_t)r * 128 + (i & 127)] : 0.f;
  }
  __syncthreads();
  const int r = tid >> 5, cg = tid & 31;
  float4 acc = {0.f, 0.f, 0.f, 0.f};
#pragma unroll
  for (int k = 0; k < 128; ++k) {
    float xv = xsh[r][k];
    float4 wv = wsh[k][cg];
    acc.x += xv * wv.x;
    acc.y += xv * wv.y;
    acc.z += xv * wv.z;
    acc.w += xv * wv.w;
  }
  if (rowbase + r < n) {
    ushort4 o;
    o.x = bf16bits(acc.x);
    o.y = bf16bits(acc.y);
    o.z = bf16bits(acc.z);
    o.w = bf16bits(acc.w);
    ((ushort4*)y)[(size_t)(rowbase + r) * 32 + cg] = o;
  }
}

__global__ void hist_kernel(const int* __restrict__ rows, int* counts, int E) {
  int e = blockIdx.x * 256 + threadIdx.x;
  if (e < E) atomicAdd(&counts[rows[e]], 1);
}

// Block-level exclusive scan (1024/block), emits block sums.
__global__ __launch_bounds__(1024) void scan1(const int* __restrict__ counts,
                                              int* __restrict__ rowptr,
                                              int* __restrict__ bsum, int n) {
  __shared__ int sh[1024];
  const int tid = threadIdx.x;
  const int i = blockIdx.x * 1024 + tid;
  int v = (i < n) ? counts[i] : 0;
  sh[tid] = v;
  __syncthreads();
  for (int off = 1; off < 1024; off <<= 1) {
    int t = (tid >= off) ? sh[tid - off] : 0;
    __syncthreads();
    sh[tid] += t;
    __syncthreads();
  }
  if (i < n) rowptr[i] = sh[tid] - v;  // exclusive
  if (tid == 1023) bsum[blockIdx.x] = sh[1023];
}

__global__ void scan2(int* bsum, int* rowptr, int nb, int n) {
  if (threadIdx.x == 0 && blockIdx.x == 0) {
    int run = 0;
    for (int b = 0; b < nb; ++b) {
      int t = bsum[b];
      bsum[b] = run;
      run += t;
    }
    rowptr[n] = run;  // == E
  }
}

__global__ __launch_bounds__(1024) void scan3(int* __restrict__ rowptr,
                                              int* __restrict__ offsets,
                                              const int* __restrict__ bsum, int n) {
  int i = blockIdx.x * 1024 + threadIdx.x;
  if (i < n) {
    int v = rowptr[i] + bsum[blockIdx.x];
    rowptr[i] = v;
    offsets[i] = v;  // running cursors for scatter
  }
}

__global__ void scatter_kernel(const int* __restrict__ rows,
                               const int* __restrict__ cols,
                               const float* __restrict__ vals, int* offsets,
                               int2* __restrict__ edges, int E) {
  int e = blockIdx.x * 256 + threadIdx.x;
  if (e < E) {
    int p = atomicAdd(&offsets[rows[e]], 1);
    edges[p] = make_int2(cols[e], __float_as_int(vals[e]));
  }
}

// One block (128 threads) per row; thread f owns feature f.
// dst = filter[row] * (A * src), stored bf16.
__global__ __launch_bounds__(128) void spmm_mid(
    const int* __restrict__ rowptr, const int2* __restrict__ edges,
    const __hip_bfloat16* __restrict__ src, __hip_bfloat16* __restrict__ dst,
    const float* __restrict__ filt) {
  const int row = blockIdx.x;
  const int f = threadIdx.x;
  const int e0 = rowptr[row], e1 = rowptr[row + 1];
  float acc = 0.f;
  int e = e0;
  for (; e + 1 < e1; e += 2) {
    int2 d0 = edges[e], d1 = edges[e + 1];
    float s0 = __bfloat162float(src[(size_t)d0.x * 128 + f]);
    float s1 = __bfloat162float(src[(size_t)d1.x * 128 + f]);
    acc += __int_as_float(d0.y) * s0;
    acc += __int_as_float(d1.y) * s1;
  }
  if (e < e1) {
    int2 d = edges[e];
    acc += __int_as_float(d.y) * __bfloat162float(src[(size_t)d.x * 128 + f]);
  }
  acc *= filt[row];
  dst[(size_t)row * 128 + f] = __float2bfloat16(acc);
}

// out = (accumulate ? out : 0) + A * src
__global__ __launch_bounds__(128) void spmm_out(
    const int* __restrict__ rowptr, const int2* __restrict__ edges,
    const __hip_bfloat16* __restrict__ src, float* __restrict__ out,
    int accumulate) {
  const int row = blockIdx.x;
  const int f = threadIdx.x;
  const int e0 = rowptr[row], e1 = rowptr[row + 1];
  float acc = 0.f;
  int e = e0;
  for (; e + 1 < e1; e += 2) {
    int2 d0 = edges[e], d1 = edges[e + 1];
    float s0 = __bfloat162float(src[(size_t)d0.x * 128 + f]);
    float s1 = __bfloat162float(src[(size_t)d1.x * 128 + f]);
    acc += __int_as_float(d0.y) * s0;
    acc += __int_as_float(d1.y) * s1;
  }
  if (e < e1) {
    int2 d = edges[e];
    acc += __int_as_float(d.y) * __bfloat162float(src[(size_t)d.x * 128 + f]);
  }
  float* o = &out[(size_t)row * 128 + f];
  *o = accumulate ? (*o + acc) : acc;
}

extern "C" void kernel_launch(void* const* d_in, const int* in_sizes, int n_in,
                              void* d_out, int out_size, void* d_ws, size_t ws_size,
                              hipStream_t stream) {
  const float* x = (const float*)d_in[0];
  const float* w = (const float*)d_in[1];
  const float* filt[3] = {(const float*)d_in[2], (const float*)d_in[3],
                          (const float*)d_in[4]};
  const int* idx[3] = {(const int*)d_in[5], (const int*)d_in[7],
                       (const int*)d_in[9]};
  const float* val[3] = {(const float*)d_in[6], (const float*)d_in[8],
                         (const float*)d_in[10]};
  const int N = in_sizes[2];  // filter1 is [N,1]
  const int E = in_sizes[6];  // val1 is [E]
  float* out = (float*)d_out;

  char* ws = (char*)d_ws;
  const size_t NF16 = (size_t)N * 128 * sizeof(__hip_bfloat16);
  __hip_bfloat16* xW = (__hip_bfloat16*)ws;
  __hip_bfloat16* t = (__hip_bfloat16*)(ws + NF16);
  size_t off = 2 * NF16;
  int* rowptr = (int*)(ws + off);
  off += (((size_t)(N + 1) * 4) + 255) & ~(size_t)255;
  int* offsets = (int*)(ws + off);
  off += (((size_t)N * 4) + 255) & ~(size_t)255;
  int* bsum = (int*)(ws + off);
  off += 4096;
  int2* edges = (int2*)(ws + off);
  off += (size_t)E * 8;
  (void)ws_size;  // ~78 MB needed; round-1 confirmed enough available

  // 1) xW = bf16(x @ W)
  gemm128<<<(N + 7) / 8, 256, 0, stream>>>(x, w, xW, N);

  const int nb = (N + 1023) / 1024;
  for (int b = 0; b < 3; ++b) {
    (void)hipMemsetAsync(offsets, 0, (size_t)N * 4, stream);
    hist_kernel<<<(E + 255) / 256, 256, 0, stream>>>(idx[b], offsets, E);
    scan1<<<nb, 1024, 0, stream>>>(offsets, rowptr, bsum, N);
    scan2<<<1, 64, 0, stream>>>(bsum, rowptr, nb, N);
    scan3<<<nb, 1024, 0, stream>>>(rowptr, offsets, bsum, N);
    scatter_kernel<<<(E + 255) / 256, 256, 0, stream>>>(
        idx[b], idx[b] + E, val[b], offsets, edges, E);
    // t = bf16(filter_b . (A_b * xW))
    spmm_mid<<<N, 128, 0, stream>>>(rowptr, edges, xW, t, filt[b]);
    // out (b==0: =, else: +=) A_b * t
    spmm_out<<<N, 128, 0, stream>>>(rowptr, edges, t, out, b > 0 ? 1 : 0);
  }
}